// Round 5
// baseline (269.791 us; speedup 1.0000x reference)
//
#include <hip/hip_runtime.h>

// DilatedReparamBlock folded into one 13x13 depthwise conv + bias.
//
// R8: fewer LDS reads via bigger ky-groups, weights in VGPRs.
// R7 post-mortem: conflict cycles/read are CONSTANT across layouts
// (R3 13.2, R7 14.1) -> the ~26 cyc per dense wave64 b128 is intrinsic
// (8 words/bank minimum); the only LDS lever is read COUNT.
//  - ky split {0..6}, {7..12}: 13 + 12 input-row passes = 125 b128
//    window reads/lane (was 185, -32%; info-theoretic min 95).
//  - group weights (7x13 / 6x13) in VGPRs via plain LDS broadcast reads
//    (readfirstlane dropped); ~180 VGPR peak is free: occupancy is
//    LDS-capped at 8 waves/CU (2/SIMD) regardless.
//  - everything else = R7 (64 thr, 7x8-col tiles, PW=68, reg prefetch).

#define CCH 384
#define SP 56
#define PW 68              // 56 + 2*6 padding
#define NPLANES (16*384)

__global__ __launch_bounds__(64, 2) void drb_conv13_r8(
    const float* __restrict__ x,
    const float* __restrict__ w_lk, const float* __restrict__ w_b0,
    const float* __restrict__ w_b1, const float* __restrict__ w_b2,
    const float* __restrict__ w_b3, const float* __restrict__ w_b4,
    const float* __restrict__ w_b5,
    const float* __restrict__ gamma, const float* __restrict__ beta,
    const float* __restrict__ mean, const float* __restrict__ var,
    float* __restrict__ out)
{
    __shared__ __align__(16) float sx[PW * PW];   // 18496 B padded plane
    __shared__ __align__(16) float sw[13 * 16];   // merged weights, rows padded to 16

    const int plane = blockIdx.x;                 // n*384 + c
    const int c = plane % CCH;
    const int tid = threadIdx.x;
    const float* __restrict__ xp = x + (size_t)plane * (SP * SP);

    // --- prefetch plane into registers (HBM latency hides under LDS init) ---
    float4 stage[13];
    #pragma unroll
    for (int k = 0; k < 13; k++) {
        int i4 = tid + 64 * k;
        if (i4 < SP * SP / 4) stage[k] = ((const float4*)xp)[i4];
    }

    // --- BN fold constants (wave-uniform -> scalar loads) ---
    float S[7];
    float bias = 0.f;
    #pragma unroll
    for (int j = 0; j < 7; j++) {
        float inv = gamma[j * CCH + c] * rsqrtf(var[j * CCH + c] + 1e-5f);
        S[j] = inv;
        bias += beta[j * CCH + c] - mean[j * CCH + c] * inv;
    }

    // --- zero padded tile (b128 stores); single wave -> ops stay ordered ---
    {
        float4 z = make_float4(0.f, 0.f, 0.f, 0.f);
        #pragma unroll
        for (int k = 0; k < 19; k++) {
            int i = tid + 64 * k;
            if (i < PW * PW / 4) ((float4*)sx)[i] = z;
        }
    }

    // --- build merged 13x13 weights (208 slots incl. row pad) ---
    #pragma unroll
    for (int k = 0; k < 4; k++) {
        int t = tid + 64 * k;
        if (t < 13 * 16) {
            int ky = t >> 4, kx = t & 15;
            float w = 0.f;
            if (kx < 13) {
                w = S[0] * w_lk[c * 169 + ky * 13 + kx];                   // 13x13 d1
                if (ky >= 4 && ky <= 8 && kx >= 4 && kx <= 8)              // 5x5 d1 @4
                    w += S[1] * w_b0[c * 25 + (ky - 4) * 5 + (kx - 4)];
                if (ky >= 3 && ky <= 9 && kx >= 3 && kx <= 9)              // 7x7 d1 @3
                    w += S[2] * w_b1[c * 49 + (ky - 3) * 7 + (kx - 3)];
                if (!(ky & 1) && !(kx & 1))                                // 7x7 d2
                    w += S[3] * w_b2[c * 49 + (ky >> 1) * 7 + (kx >> 1)];
                if (ky >= 3 && ky <= 9 && (ky - 3) % 3 == 0 &&
                    kx >= 3 && kx <= 9 && (kx - 3) % 3 == 0)               // 3x3 d3
                    w += S[4] * w_b3[c * 9 + ((ky - 3) / 3) * 3 + (kx - 3) / 3];
                if (ky >= 2 && ky <= 10 && (ky - 2) % 4 == 0 &&
                    kx >= 2 && kx <= 10 && (kx - 2) % 4 == 0)              // 3x3 d4
                    w += S[5] * w_b4[c * 9 + ((ky - 2) / 4) * 3 + (kx - 2) / 4];
                if (ky >= 1 && ky <= 11 && (ky - 1) % 5 == 0 &&
                    kx >= 1 && kx <= 11 && (kx - 1) % 5 == 0)              // 3x3 d5
                    w += S[6] * w_b5[c * 9 + ((ky - 1) / 5) * 3 + (kx - 1) / 5];
            }
            sw[t] = w;
        }
    }

    // --- write staged plane into LDS (after zero; same-wave LDS ops ordered) ---
    #pragma unroll
    for (int k = 0; k < 13; k++) {
        int i4 = tid + 64 * k;
        if (i4 < SP * SP / 4) {
            int r = i4 / 14;                 // 14 float4 per 56-wide row
            int col = (i4 - r * 14) * 4;
            float* d = &sx[(r + 6) * PW + col + 6];   // word-even -> 8B aligned
            ((float2*)d)[0] = make_float2(stage[k].x, stage[k].y);
            ((float2*)d)[1] = make_float2(stage[k].z, stage[k].w);
        }
    }
    __syncthreads();

    // --- compute: lane (xg,yg) -> out rows [7yg..7yg+6], cols [8xg..8xg+7] ---
    const int xg = tid & 7;
    const int yg = tid >> 3;
    const int xgc = (xg < 7) ? xg : 3;       // idle lane: same-address broadcast with xg=3
    const int Yb = yg * 7;
    const float* __restrict__ sbase = &sx[Yb * PW + 8 * xgc];

    float acc[7][8];
    #pragma unroll
    for (int r = 0; r < 7; r++)
        #pragma unroll
        for (int j = 0; j < 8; j++) acc[r][j] = 0.f;

    // ===== group A: ky 0..6, input rows i = 0..12 (13 reads) =====
    {
        float wA[7][13];   // wave-uniform -> broadcast LDS reads into VGPRs
        #pragma unroll
        for (int dy = 0; dy < 7; dy++) {
            const float* wr = &sw[dy * 16];
            #pragma unroll
            for (int q = 0; q < 3; q++) {
                float4 t = ((const float4*)wr)[q];
                wA[dy][4*q+0] = t.x; wA[dy][4*q+1] = t.y;
                wA[dy][4*q+2] = t.z; wA[dy][4*q+3] = t.w;
            }
            wA[dy][12] = wr[12];
        }
        #pragma unroll
        for (int i = 0; i < 13; i++) {
            float4 win4[5];
            #pragma unroll
            for (int q = 0; q < 5; q++)
                win4[q] = *(const float4*)(sbase + i * PW + 4 * q);
            const float* win = (const float*)win4;
            #pragma unroll
            for (int dy = 0; dy < 7; dy++) {
                const int r = i - dy;
                if (r >= 0 && r < 7) {
                    #pragma unroll
                    for (int kx = 0; kx < 13; kx++) {
                        const float wv = wA[dy][kx];
                        #pragma unroll
                        for (int j = 0; j < 8; j++)
                            acc[r][j] = fmaf(wv, win[kx + j], acc[r][j]);
                    }
                }
            }
        }
    }

    // ===== group B: ky 7..12, input rows i = 7..18 (12 reads) =====
    {
        float wB[6][13];
        #pragma unroll
        for (int dy = 0; dy < 6; dy++) {
            const float* wr = &sw[(7 + dy) * 16];
            #pragma unroll
            for (int q = 0; q < 3; q++) {
                float4 t = ((const float4*)wr)[q];
                wB[dy][4*q+0] = t.x; wB[dy][4*q+1] = t.y;
                wB[dy][4*q+2] = t.z; wB[dy][4*q+3] = t.w;
            }
            wB[dy][12] = wr[12];
        }
        #pragma unroll
        for (int i = 7; i < 19; i++) {
            float4 win4[5];
            #pragma unroll
            for (int q = 0; q < 5; q++)
                win4[q] = *(const float4*)(sbase + i * PW + 4 * q);
            const float* win = (const float*)win4;
            #pragma unroll
            for (int dy = 0; dy < 6; dy++) {
                const int r = i - 7 - dy;    // ky = 7+dy
                if (r >= 0 && r < 7) {
                    #pragma unroll
                    for (int kx = 0; kx < 13; kx++) {
                        const float wv = wB[dy][kx];
                        #pragma unroll
                        for (int j = 0; j < 8; j++)
                            acc[r][j] = fmaf(wv, win[kx + j], acc[r][j]);
                    }
                }
            }
        }
    }

    // --- epilogue: +bias, 2x float4 stores per row, idle col group masked ---
    if (xg < 7) {
        float* op = out + (size_t)plane * (SP * SP) + Yb * SP + 8 * xg;
        #pragma unroll
        for (int r = 0; r < 7; r++) {
            float4 v0 = make_float4(acc[r][0] + bias, acc[r][1] + bias,
                                    acc[r][2] + bias, acc[r][3] + bias);
            float4 v1 = make_float4(acc[r][4] + bias, acc[r][5] + bias,
                                    acc[r][6] + bias, acc[r][7] + bias);
            *(float4*)(op + r * SP) = v0;
            *(float4*)(op + r * SP + 4) = v1;
        }
    }
}

extern "C" void kernel_launch(void* const* d_in, const int* in_sizes, int n_in,
                              void* d_out, int out_size, void* d_ws, size_t ws_size,
                              hipStream_t stream) {
    const float* x    = (const float*)d_in[0];
    const float* w_lk = (const float*)d_in[1];
    const float* w_b0 = (const float*)d_in[2];
    const float* w_b1 = (const float*)d_in[3];
    const float* w_b2 = (const float*)d_in[4];
    const float* w_b3 = (const float*)d_in[5];
    const float* w_b4 = (const float*)d_in[6];
    const float* w_b5 = (const float*)d_in[7];
    const float* bn_g = (const float*)d_in[8];
    const float* bn_b = (const float*)d_in[9];
    const float* bn_m = (const float*)d_in[10];
    const float* bn_v = (const float*)d_in[11];
    float* out = (float*)d_out;

    drb_conv13_r8<<<dim3(NPLANES), dim3(64), 0, stream>>>(
        x, w_lk, w_b0, w_b1, w_b2, w_b3, w_b4, w_b5,
        bn_g, bn_b, bn_m, bn_v, out);
}